// Round 5
// baseline (5478.645 us; speedup 1.0000x reference)
//
#include <hip/hip_runtime.h>
#include <hip/hip_bf16.h>

typedef __attribute__((ext_vector_type(8))) short bf16x8;   // MFMA A/B frag (16B)
typedef __attribute__((ext_vector_type(4))) float f32x4;    // MFMA C/D frag
using bf16 = __hip_bfloat16;
typedef unsigned long long u64;

constexpr int BB = 64, TT = 256, DIN = 512, HH = 1024, DOUT = 512;
constexpr int P0 = 1544;   // LDS pitch for W0 rows (1536 + 8)
constexpr int P1 = 2056;   // LDS pitch for W1 rows (2048 + 8)

#define MFMA16(a, b, c) __builtin_amdgcn_mfma_f32_16x16x32_bf16((a), (b), (c), 0, 0, 0)

__device__ __forceinline__ short f2b(float f) {
  __hip_bfloat16 h = __float2bfloat16(f);           // RNE
  return *reinterpret_cast<short*>(&h);
}

// gate math: z -> (h bf16 bits), updates c register
__device__ __forceinline__ unsigned short gates(const float zv[4], const float br[4],
                                                float scale, float& cr, bool first) {
  float zf = (zv[0] + br[0]) * scale;
  float zi = (zv[1] + br[1]) * scale;
  float zo = (zv[2] + br[2]) * scale;
  float zg = (zv[3] + br[3]) * scale;
  float f = 1.0f / (1.0f + __expf(-zf));
  float i = 1.0f / (1.0f + __expf(-zi));
  float o = 1.0f / (1.0f + __expf(-zo));
  float g = tanhf(zg);
  float cn = f * (first ? 0.0f : cr) + i * g;
  cr = cn;
  __hip_bfloat16 hv = __float2bfloat16(o * tanhf(cn));
  return *reinterpret_cast<unsigned short*>(&hv);
}

// ---------------- persistent kernel: 256 blocks x 256 threads, 1 block/CU ----------------
// Block wg owns h-cols [4wg,4wg+4) of both layers -> its 16 z-cols (gate=n>>2, hcol=wg*4+(n&3)).
// Waves split K; block-reduce z via LDS. c in registers; h published via agent-scope (sc1,
// write-through) 8B atomic stores; barrier = per-block flag array; acquire = agent fence.
// MLP strategy: occupancy is LDS-bound at 1 block/CU (1 wave/SIMD) -> latency hiding must be
// ILP. All A-operand loads are issued in fully-unrolled 16/32-wide register-prefetch bursts.
__global__ void __launch_bounds__(256, 1)
lstm_persist(const float* __restrict__ x,  const float* __restrict__ W0,
             const float* __restrict__ b0, const float* __restrict__ W1,
             const float* __restrict__ b1, const float* __restrict__ Wfc,
             const float* __restrict__ bfc,
             bf16* __restrict__ h0, bf16* __restrict__ h1,
             unsigned* __restrict__ flags, float* __restrict__ out) {
  __shared__ unsigned short lw0[16 * P0];            // 49.4 KB  W0^T cols (this block), bf16
  __shared__ unsigned short lw1[16 * P1];            // 65.8 KB  W1^T cols (this block), bf16
  __shared__ float zbuf[4][4][16][17];               // 17.4 KB  cross-wave z partials
  __shared__ unsigned short hs[64][4];               // 0.5 KB   h-tile staging for publish

  const int tid  = threadIdx.x;
  const int wg   = blockIdx.x;
  const int lane = tid & 63;
  const int v    = tid >> 6;          // wave id = K-quarter
  const int n    = lane & 15;         // MFMA col / A row-within-tile
  const int oct  = lane >> 4;         // k-octet
  const int mg   = tid & 63;          // epilogue: batch row
  const int hq   = tid >> 6;          // epilogue: hcol offset 0..3
  const int hcol = wg * 4 + hq;
  const float S0 = 1.0f / sqrtf((float)(DIN + HH));
  const float S1 = 1.0f / sqrtf((float)(HH + HH));

  // per-thread recurrent state + biases in registers (never exchanged)
  float c0r = 0.0f, c1r = 0.0f;
  float b0r[4], b1r[4];
#pragma unroll
  for (int g = 0; g < 4; ++g) { b0r[g] = b0[g * HH + hcol]; b1r[g] = b1[g * HH + hcol]; }

  // ---- stage this block's 16 columns of W0/W1 into LDS (fp32 -> bf16, transposed) ----
  {
    const int g = tid >> 6, kw = tid & 63;
    const int col0 = g * HH + wg * 4;
    for (int k = kw; k < DIN + HH; k += 64) {
      float4 u = *(const float4*)(W0 + (size_t)k * 4096 + col0);
      lw0[(g * 4 + 0) * P0 + k] = (unsigned short)f2b(u.x);
      lw0[(g * 4 + 1) * P0 + k] = (unsigned short)f2b(u.y);
      lw0[(g * 4 + 2) * P0 + k] = (unsigned short)f2b(u.z);
      lw0[(g * 4 + 3) * P0 + k] = (unsigned short)f2b(u.w);
    }
    for (int k = kw; k < 2 * HH; k += 64) {
      float4 u = *(const float4*)(W1 + (size_t)k * 4096 + col0);
      lw1[(g * 4 + 0) * P1 + k] = (unsigned short)f2b(u.x);
      lw1[(g * 4 + 1) * P1 + k] = (unsigned short)f2b(u.y);
      lw1[(g * 4 + 2) * P1 + k] = (unsigned short)f2b(u.z);
      lw1[(g * 4 + 3) * P1 + k] = (unsigned short)f2b(u.w);
    }
  }
  __syncthreads();

  f32x4 z0a[4], z1a[4];
  float zv[4];

  // ---- x-part of layer0(t): 16-frag register prefetch burst, then cvt+MFMA ----
  auto xpart = [&](int t) {
    float4 xf[16][2];
#pragma unroll
    for (int it = 0; it < 16; ++it) {
      const int s = it & 3, rt = it >> 2;
      const float* p = x + ((size_t)(rt * 16 + n) * TT + t) * DIN + v * 128 + s * 32 + oct * 8;
      xf[it][0] = *(const float4*)p;
      xf[it][1] = *(const float4*)(p + 4);
    }
#pragma unroll
    for (int it = 0; it < 16; ++it) {
      const int s = it & 3, rt = it >> 2;
      bf16x8 a;
      a[0] = f2b(xf[it][0].x); a[1] = f2b(xf[it][0].y);
      a[2] = f2b(xf[it][0].z); a[3] = f2b(xf[it][0].w);
      a[4] = f2b(xf[it][1].x); a[5] = f2b(xf[it][1].y);
      a[6] = f2b(xf[it][1].z); a[7] = f2b(xf[it][1].w);
      bf16x8 bw = *(const bf16x8*)&lw0[n * P0 + v * 128 + s * 32 + oct * 8];
      z0a[rt] = MFMA16(a, bw, z0a[rt]);
    }
  };

  // ---- 32-frag burst load of one h matrix (this wave's K-quarter, 4 row-tiles) ----
  auto load32 = [&](bf16x8 ah[32], const bf16* hp) {
#pragma unroll
    for (int it = 0; it < 32; ++it) {
      const int s = it & 7, rt = it >> 3;
      ah[it] = *(const bf16x8*)(hp + (size_t)(rt * 16 + n) * HH + v * 256 + s * 32 + oct * 8);
    }
  };

  // publish: wave 0 stores 64 rows x 8B (4 bf16) write-through at agent scope
  auto publish = [&](bf16* dst) {
    if (tid < 64) {
      u64 val = *(const u64*)&hs[tid][0];
      __hip_atomic_store((u64*)(dst + (size_t)tid * HH + wg * 4), val,
                         __ATOMIC_RELAXED, __HIP_MEMORY_SCOPE_AGENT);
    }
  };
  auto flag_release = [&](unsigned val) {
    if (tid < 64) __builtin_amdgcn_s_waitcnt(0);     // wave0: drain sc1 h stores
    if (tid == 0)
      __hip_atomic_store(&flags[wg], val, __ATOMIC_RELAXED, __HIP_MEMORY_SCOPE_AGENT);
  };
  auto bar_wait = [&](unsigned target) {
    while (__hip_atomic_load(&flags[tid], __ATOMIC_RELAXED, __HIP_MEMORY_SCOPE_AGENT) < target)
      __builtin_amdgcn_s_sleep(1);
    __syncthreads();
    __builtin_amdgcn_fence(__ATOMIC_ACQUIRE, "agent");   // buffer_inv: drop stale L2 h lines
  };
  // z partial reduce: write partials, sync, sum 4 waves
  auto zreduce = [&](f32x4 za[4]) {
#pragma unroll
    for (int rt = 0; rt < 4; ++rt)
#pragma unroll
      for (int r = 0; r < 4; ++r) zbuf[v][rt][oct * 4 + r][n] = za[rt][r];
    __syncthreads();
#pragma unroll
    for (int g = 0; g < 4; ++g)
      zv[g] = zbuf[0][mg >> 4][mg & 15][g * 4 + hq] + zbuf[1][mg >> 4][mg & 15][g * 4 + hq] +
              zbuf[2][mg >> 4][mg & 15][g * 4 + hq] + zbuf[3][mg >> 4][mg & 15][g * 4 + hq];
  };

  // =================== window 0: layer0(0), x-part only ===================
#pragma unroll
  for (int rt = 0; rt < 4; ++rt) z0a[rt] = (f32x4){0.f, 0.f, 0.f, 0.f};
  xpart(0);
  zreduce(z0a);
  hs[mg][hq] = gates(zv, b0r, S0, c0r, true);
  __syncthreads();
  publish(h0 /*buf0*/);
  flag_release(1u);

  // =================== windows 1..255: layer1(t-1) + layer0(t) ===================
  for (int t = 1; t < TT; ++t) {
    // x-part of layer0(t): no recurrent dependency, hides barrier latency
#pragma unroll
    for (int rt = 0; rt < 4; ++rt) z0a[rt] = (f32x4){0.f, 0.f, 0.f, 0.f};
    xpart(t);

    bar_wait((unsigned)t);   // all blocks finished window t-1: h0(t-1), h1(t-2) visible

    const bf16* h0p = h0 + ((t - 1) & 1) * (BB * HH);   // h0(t-1)
    const bf16* h1p = h1 + (t & 1) * (BB * HH);         // h1(t-2)
#pragma unroll
    for (int rt = 0; rt < 4; ++rt) z1a[rt] = (f32x4){0.f, 0.f, 0.f, 0.f};

    // ---- h0 segment: 32-frag burst, dual consume (layer0 W0[512+k], layer1 W1[k]) ----
    {
      bf16x8 ah[32];
      load32(ah, h0p);
#pragma unroll
      for (int it = 0; it < 32; ++it) {
        const int s = it & 7, rt = it >> 3;
        const int kp = v * 256 + s * 32 + oct * 8;
        bf16x8 bw0 = *(const bf16x8*)&lw0[n * P0 + 512 + kp];
        bf16x8 bw1 = *(const bf16x8*)&lw1[n * P1 + kp];
        z0a[rt] = MFMA16(ah[it], bw0, z0a[rt]);
        z1a[rt] = MFMA16(ah[it], bw1, z1a[rt]);
      }
    }
    // ---- h1 segment of layer1(t-1): 32-frag burst, consume W1[1024+k] ----
    if (t >= 2) {
      bf16x8 ah[32];
      load32(ah, h1p);
#pragma unroll
      for (int it = 0; it < 32; ++it) {
        const int s = it & 7, rt = it >> 3;
        const int kp = v * 256 + s * 32 + oct * 8;
        bf16x8 bw = *(const bf16x8*)&lw1[n * P1 + 1024 + kp];
        z1a[rt] = MFMA16(ah[it], bw, z1a[rt]);
      }
    }

    // ---- reduce z1 -> cell1 -> publish h1(t-1) ----
    zreduce(z1a);
    hs[mg][hq] = gates(zv, b1r, S1, c1r, t == 1);
    __syncthreads();                      // zbuf reads done + hs complete
    publish(h1 + ((t - 1) & 1) * (BB * HH));
    // ---- reduce z0 -> cell0 -> publish h0(t) ----
    zreduce(z0a);
    hs[mg][hq] = gates(zv, b0r, S0, c0r, false);
    __syncthreads();
    publish(h0 + (t & 1) * (BB * HH));
    flag_release((unsigned)t + 1u);
  }

  // =================== final: layer1(255) ===================
  bar_wait(256u);
  {
    const bf16* h0p = h0 + 1 * (BB * HH);   // h0(255)
    const bf16* h1p = h1 + 0 * (BB * HH);   // h1(254)
#pragma unroll
    for (int rt = 0; rt < 4; ++rt) z1a[rt] = (f32x4){0.f, 0.f, 0.f, 0.f};
    {
      bf16x8 ah[32];
      load32(ah, h0p);
#pragma unroll
      for (int it = 0; it < 32; ++it) {
        const int s = it & 7, rt = it >> 3;
        bf16x8 bw = *(const bf16x8*)&lw1[n * P1 + v * 256 + s * 32 + oct * 8];
        z1a[rt] = MFMA16(ah[it], bw, z1a[rt]);
      }
    }
    {
      bf16x8 ah[32];
      load32(ah, h1p);
#pragma unroll
      for (int it = 0; it < 32; ++it) {
        const int s = it & 7, rt = it >> 3;
        bf16x8 bw = *(const bf16x8*)&lw1[n * P1 + 1024 + v * 256 + s * 32 + oct * 8];
        z1a[rt] = MFMA16(ah[it], bw, z1a[rt]);
      }
    }
    zreduce(z1a);
    hs[mg][hq] = gates(zv, b1r, S1, c1r, false);
    __syncthreads();
    publish(h1 + 1 * (BB * HH));           // h1(255) -> buf1
    flag_release(257u);
  }

  // ============ final FC: out = h1(255) @ Wfc + bfc (blocks 0..31) ============
  if (wg < DOUT / 16) {
    bar_wait(257u);
    {  // stage Wfc cols [wg*16, wg*16+16) into lw0 region (fp32 -> bf16)
      const int q = tid >> 6, kw = tid & 63;
      for (int k = kw; k < HH; k += 64) {
        float4 u = *(const float4*)(Wfc + (size_t)k * DOUT + wg * 16 + q * 4);
        lw0[(q * 4 + 0) * P0 + k] = (unsigned short)f2b(u.x);
        lw0[(q * 4 + 1) * P0 + k] = (unsigned short)f2b(u.y);
        lw0[(q * 4 + 2) * P0 + k] = (unsigned short)f2b(u.z);
        lw0[(q * 4 + 3) * P0 + k] = (unsigned short)f2b(u.w);
      }
    }
    __syncthreads();
    const bf16* h1f = h1 + 1 * (BB * HH);   // h1(255)
    f32x4 acc0 = {0.f, 0.f, 0.f, 0.f}, acc1 = {0.f, 0.f, 0.f, 0.f};
    {
      bf16x8 ah[16];
#pragma unroll
      for (int it = 0; it < 16; ++it)
        ah[it] = *(const bf16x8*)(h1f + (size_t)(v * 16 + n) * HH + it * 64 + oct * 8);
#pragma unroll
      for (int it = 0; it < 16; ++it) {
        bf16x8 bwA = *(const bf16x8*)&lw0[n * P0 + it * 64 + oct * 8];
        acc0 = MFMA16(ah[it], bwA, acc0);
      }
      bf16x8 ah2[16];
#pragma unroll
      for (int it = 0; it < 16; ++it)
        ah2[it] = *(const bf16x8*)(h1f + (size_t)(v * 16 + n) * HH + it * 64 + 32 + oct * 8);
#pragma unroll
      for (int it = 0; it < 16; ++it) {
        bf16x8 bwB = *(const bf16x8*)&lw0[n * P0 + it * 64 + 32 + oct * 8];
        acc1 = MFMA16(ah2[it], bwB, acc1);
      }
    }
    float bb = bfc[wg * 16 + n];
#pragma unroll
    for (int r = 0; r < 4; ++r) {
      int row = v * 16 + oct * 4 + r;
      out[(size_t)row * DOUT + wg * 16 + n] = acc0[r] + acc1[r] + bb;
    }
  }
}

extern "C" void kernel_launch(void* const* d_in, const int* in_sizes, int n_in,
                              void* d_out, int out_size, void* d_ws, size_t ws_size,
                              hipStream_t stream) {
  const float* x   = (const float*)d_in[0];
  const float* W0  = (const float*)d_in[1];
  const float* b0  = (const float*)d_in[2];
  const float* W1  = (const float*)d_in[3];
  const float* b1  = (const float*)d_in[4];
  const float* Wfc = (const float*)d_in[5];
  const float* bfc = (const float*)d_in[6];

  // ---- workspace (~0.5 MB): flag array + h double-buffers ----
  char* ws = (char*)d_ws;
  size_t off = 0;
  unsigned* flags = (unsigned*)(ws + off); off += 4096;                   // 256 flags (1KB used)
  bf16* h0 = (bf16*)(ws + off); off += (size_t)2 * BB * HH * 2;           // h0 double-buffer
  bf16* h1 = (bf16*)(ws + off); off += (size_t)2 * BB * HH * 2;           // h1 double-buffer

  hipMemsetAsync(flags, 0, 4096, stream);   // ws re-poisoned each call; flags must start at 0

  lstm_persist<<<dim3(256), dim3(256), 0, stream>>>(
      x, W0, b0, W1, b1, Wfc, bfc, h0, h1, flags, (float*)d_out);
}

// Round 6
// 2739.790 us; speedup vs baseline: 1.9997x; 1.9997x over previous
//
#include <hip/hip_runtime.h>
#include <hip/hip_bf16.h>

typedef __attribute__((ext_vector_type(8))) short bf16x8;   // MFMA A/B frag (16B)
typedef __attribute__((ext_vector_type(4))) float f32x4;    // MFMA C/D frag
using bf16 = __hip_bfloat16;
typedef unsigned long long u64;

constexpr int BB = 64, TT = 256, DIN = 512, HH = 1024, DOUT = 512;
constexpr int P0 = 1544;   // LDS pitch for W0 rows (1536 + 8)
constexpr int P1 = 2056;   // LDS pitch for W1 rows (2048 + 8)
constexpr int HWORDS = 8192;   // one h matrix half-array: 128 koct x 64 rows (u64 each)

#define MFMA16(a, b, c) __builtin_amdgcn_mfma_f32_16x16x32_bf16((a), (b), (c), 0, 0, 0)
#define ALOAD(p)  __hip_atomic_load((p),  __ATOMIC_RELAXED, __HIP_MEMORY_SCOPE_AGENT)
#define ASTORE(p, v) __hip_atomic_store((p), (v), __ATOMIC_RELAXED, __HIP_MEMORY_SCOPE_AGENT)

union frag_u { u64 q[2]; bf16x8 f; };

__device__ __forceinline__ short f2b(float f) {
  __hip_bfloat16 h = __float2bfloat16(f);           // RNE
  return *reinterpret_cast<short*>(&h);
}

// gate math: z -> (h bf16 bits), updates c register
__device__ __forceinline__ unsigned short gates(const float zv[4], const float br[4],
                                                float scale, float& cr, bool first) {
  float zf = (zv[0] + br[0]) * scale;
  float zi = (zv[1] + br[1]) * scale;
  float zo = (zv[2] + br[2]) * scale;
  float zg = (zv[3] + br[3]) * scale;
  float f = 1.0f / (1.0f + __expf(-zf));
  float i = 1.0f / (1.0f + __expf(-zi));
  float o = 1.0f / (1.0f + __expf(-zo));
  float g = tanhf(zg);
  float cn = f * (first ? 0.0f : cr) + i * g;
  cr = cn;
  __hip_bfloat16 hv = __float2bfloat16(o * tanhf(cn));
  return *reinterpret_cast<unsigned short*>(&hv);
}

// ---------------- persistent kernel: 256 blocks x 256 threads, 1 block/CU ----------------
// Block wg owns h-cols [4wg,4wg+4) -> its 16 z-cols (gate=n>>2, hcol=wg*4+(n&3)). Waves split
// K; block-reduce z via LDS. FENCE-FREE coherence: h exchanged only through agent-scope (sc1)
// relaxed atomics in a split-octet layout (two half-arrays [koct][row] of u64) so both publish
// stores and consume loads are fully-coalesced full sectors at the coherence point (L3).
// x/weights use normal cached loads and stay L2-resident (nothing ever invalidates L2).
// Split barriers: flagsA = h0 ready (released mid-window), flagsB = h1 ready (end of window).
__global__ void __launch_bounds__(256, 1)
lstm_persist(const float* __restrict__ x,  const float* __restrict__ W0,
             const float* __restrict__ b0, const float* __restrict__ W1,
             const float* __restrict__ b1, const float* __restrict__ Wfc,
             const float* __restrict__ bfc,
             u64* __restrict__ h0s, u64* __restrict__ h1s,
             unsigned* __restrict__ flagsA, unsigned* __restrict__ flagsB,
             float* __restrict__ out) {
  __shared__ unsigned short lw0[16 * P0];            // 49.4 KB  W0^T cols (this block), bf16
  __shared__ unsigned short lw1[16 * P1];            // 65.8 KB  W1^T cols (this block), bf16
  __shared__ float zbuf[4][4][16][17];               // 17.4 KB  cross-wave z partials
  __shared__ unsigned short hs[64][4];               // 0.5 KB   h-tile staging for publish

  const int tid  = threadIdx.x;
  const int wg   = blockIdx.x;
  const int lane = tid & 63;
  const int v    = tid >> 6;          // wave id = K-quarter
  const int n    = lane & 15;         // MFMA col / A row-within-tile
  const int oct  = lane >> 4;         // k-octet
  const int mg   = tid & 63;          // epilogue: batch row
  const int hq   = tid >> 6;          // epilogue: hcol offset 0..3
  const int hcol = wg * 4 + hq;
  const float S0 = 1.0f / sqrtf((float)(DIN + HH));
  const float S1 = 1.0f / sqrtf((float)(HH + HH));

  // per-thread recurrent state + biases in registers (never exchanged)
  float c0r = 0.0f, c1r = 0.0f;
  float b0r[4], b1r[4];
#pragma unroll
  for (int g = 0; g < 4; ++g) { b0r[g] = b0[g * HH + hcol]; b1r[g] = b1[g * HH + hcol]; }

  // ---- stage this block's 16 columns of W0/W1 into LDS (fp32 -> bf16, transposed) ----
  {
    const int g = tid >> 6, kw = tid & 63;
    const int col0 = g * HH + wg * 4;
    for (int k = kw; k < DIN + HH; k += 64) {
      float4 u = *(const float4*)(W0 + (size_t)k * 4096 + col0);
      lw0[(g * 4 + 0) * P0 + k] = (unsigned short)f2b(u.x);
      lw0[(g * 4 + 1) * P0 + k] = (unsigned short)f2b(u.y);
      lw0[(g * 4 + 2) * P0 + k] = (unsigned short)f2b(u.z);
      lw0[(g * 4 + 3) * P0 + k] = (unsigned short)f2b(u.w);
    }
    for (int k = kw; k < 2 * HH; k += 64) {
      float4 u = *(const float4*)(W1 + (size_t)k * 4096 + col0);
      lw1[(g * 4 + 0) * P1 + k] = (unsigned short)f2b(u.x);
      lw1[(g * 4 + 1) * P1 + k] = (unsigned short)f2b(u.y);
      lw1[(g * 4 + 2) * P1 + k] = (unsigned short)f2b(u.z);
      lw1[(g * 4 + 3) * P1 + k] = (unsigned short)f2b(u.w);
    }
  }
  __syncthreads();

  f32x4 z0a[4], z1a[4];
  float zv[4];

  // ---- x-part of layer0(t): cached fp32 loads + on-the-fly bf16 cvt ----
  auto xpart = [&](int t) {
#pragma unroll
    for (int s = 0; s < 4; ++s) {
      const int kp = v * 128 + s * 32 + oct * 8;
      bf16x8 bw = *(const bf16x8*)&lw0[n * P0 + kp];
#pragma unroll
      for (int rt = 0; rt < 4; ++rt) {
        const float* p = x + ((size_t)(rt * 16 + n) * TT + t) * DIN + kp;
        float4 A = *(const float4*)p, B = *(const float4*)(p + 4);
        bf16x8 a;
        a[0] = f2b(A.x); a[1] = f2b(A.y); a[2] = f2b(A.z); a[3] = f2b(A.w);
        a[4] = f2b(B.x); a[5] = f2b(B.y); a[6] = f2b(B.z); a[7] = f2b(B.w);
        z0a[rt] = MFMA16(a, bw, z0a[rt]);
      }
    }
  };

  // publish: wave 0 stores 64 rows x 8B into split-octet layout, fully coalesced (512B/wave)
  auto publish = [&](u64* dst) {
    if (tid < 64) {
      u64 val = *(const u64*)&hs[tid][0];
      ASTORE(dst + (size_t)(wg & 1) * HWORDS + (wg >> 1) * 64 + tid, val);
    }
  };
  auto flag_release = [&](unsigned* f, unsigned val) {
    if (tid < 64) __builtin_amdgcn_s_waitcnt(0);     // wave0: drain sc1 h stores
    if (tid == 0) ASTORE(f + wg, val);
  };
  auto bar_wait = [&](unsigned* f, unsigned target) {
    if (tid < 64) {                                  // only wave 0 polls (4 flags/thread)
      const u64* p = (const u64*)(f + tid * 4);
      for (;;) {
        u64 a = ALOAD(p), b = ALOAD(p + 1);
        if ((unsigned)a >= target && (unsigned)(a >> 32) >= target &&
            (unsigned)b >= target && (unsigned)(b >> 32) >= target) break;
        __builtin_amdgcn_s_sleep(1);
      }
    }
    __syncthreads();
    __builtin_amdgcn_fence(__ATOMIC_ACQUIRE, "workgroup");   // ordering only, no cache maint
  };
  auto zreduce = [&](f32x4 za[4]) {
#pragma unroll
    for (int rt = 0; rt < 4; ++rt)
#pragma unroll
      for (int r = 0; r < 4; ++r) zbuf[v][rt][oct * 4 + r][n] = za[rt][r];
    __syncthreads();
#pragma unroll
    for (int g = 0; g < 4; ++g)
      zv[g] = zbuf[0][mg >> 4][mg & 15][g * 4 + hq] + zbuf[1][mg >> 4][mg & 15][g * 4 + hq] +
              zbuf[2][mg >> 4][mg & 15][g * 4 + hq] + zbuf[3][mg >> 4][mg & 15][g * 4 + hq];
  };

  // =================== window 0: layer0(0), x-part only ===================
#pragma unroll
  for (int rt = 0; rt < 4; ++rt) z0a[rt] = (f32x4){0.f, 0.f, 0.f, 0.f};
  xpart(0);
  zreduce(z0a);
  hs[mg][hq] = gates(zv, b0r, S0, c0r, true);
  __syncthreads();
  publish(h0s + 0 * 2 * HWORDS);        // h0(0), parity 0
  flag_release(flagsA, 1u);
  flag_release(flagsB, 1u);             // vacuous h1(-1)
#pragma unroll
  for (int rt = 0; rt < 4; ++rt) z0a[rt] = (f32x4){0.f, 0.f, 0.f, 0.f};
  xpart(1);

  // =================== windows 1..255 ===================
  for (int t = 1; t < TT; ++t) {
    bar_wait(flagsA, (unsigned)t);      // h0(t-1) visible
    const u64* h0b = h0s + (size_t)(((t - 1) & 1) * 2) * HWORDS;
#pragma unroll
    for (int rt = 0; rt < 4; ++rt) z1a[rt] = (f32x4){0.f, 0.f, 0.f, 0.f};

    // ---- h0 burst (split-octet atomic loads), dual consume: z0 += h0*W0hi, z1 += h0*W1lo ----
#pragma unroll
    for (int half = 0; half < 2; ++half) {
      const int s0 = half * 4;
      u64 lo[16], hi[16];
#pragma unroll
      for (int i = 0; i < 16; ++i) {
        const int s = s0 + (i >> 2), rt = i & 3;
        const int idx = (v * 32 + s * 4 + oct) * 64 + rt * 16 + n;
        lo[i] = ALOAD(h0b + idx);
        hi[i] = ALOAD(h0b + HWORDS + idx);
      }
#pragma unroll
      for (int sj = 0; sj < 4; ++sj) {
        const int kp = v * 256 + (s0 + sj) * 32 + oct * 8;
        bf16x8 bw0 = *(const bf16x8*)&lw0[n * P0 + 512 + kp];
        bf16x8 bw1 = *(const bf16x8*)&lw1[n * P1 + kp];
#pragma unroll
        for (int rt = 0; rt < 4; ++rt) {
          frag_u u; u.q[0] = lo[sj * 4 + rt]; u.q[1] = hi[sj * 4 + rt];
          z0a[rt] = MFMA16(u.f, bw0, z0a[rt]);
          z1a[rt] = MFMA16(u.f, bw1, z1a[rt]);
        }
      }
    }

    // ---- z0 complete: cell0 -> publish h0(t) -> releaseA early ----
    zreduce(z0a);
    hs[mg][hq] = gates(zv, b0r, S0, c0r, false);
    __syncthreads();
    publish(h0s + (size_t)((t & 1) * 2) * HWORDS);
    flag_release(flagsA, (unsigned)t + 1u);

    if (t < TT - 1) {                   // overlap x(t+1) with the flagsB wait
#pragma unroll
      for (int rt = 0; rt < 4; ++rt) z0a[rt] = (f32x4){0.f, 0.f, 0.f, 0.f};
      xpart(t + 1);
    }

    // ---- h1 segment: z1 += h1(t-2)*W1hi ----
    if (t >= 2) {
      bar_wait(flagsB, (unsigned)t);    // h1(t-2) visible
      const u64* h1b = h1s + (size_t)((t & 1) * 2) * HWORDS;
#pragma unroll
      for (int half = 0; half < 2; ++half) {
        const int s0 = half * 4;
        u64 lo[16], hi[16];
#pragma unroll
        for (int i = 0; i < 16; ++i) {
          const int s = s0 + (i >> 2), rt = i & 3;
          const int idx = (v * 32 + s * 4 + oct) * 64 + rt * 16 + n;
          lo[i] = ALOAD(h1b + idx);
          hi[i] = ALOAD(h1b + HWORDS + idx);
        }
#pragma unroll
        for (int sj = 0; sj < 4; ++sj) {
          const int kp = v * 256 + (s0 + sj) * 32 + oct * 8;
          bf16x8 bw = *(const bf16x8*)&lw1[n * P1 + 1024 + kp];
#pragma unroll
          for (int rt = 0; rt < 4; ++rt) {
            frag_u u; u.q[0] = lo[sj * 4 + rt]; u.q[1] = hi[sj * 4 + rt];
            z1a[rt] = MFMA16(u.f, bw, z1a[rt]);
          }
        }
      }
    }

    // ---- cell1 -> publish h1(t-1) -> releaseB ----
    zreduce(z1a);
    hs[mg][hq] = gates(zv, b1r, S1, c1r, t == 1);
    __syncthreads();
    publish(h1s + (size_t)(((t - 1) & 1) * 2) * HWORDS);
    flag_release(flagsB, (unsigned)t + 1u);
  }

  // =================== final window: layer1(255) ===================
  {
    bar_wait(flagsA, 256u);             // h0(255), parity 1
    const u64* h0b = h0s + (size_t)(1 * 2) * HWORDS;
#pragma unroll
    for (int rt = 0; rt < 4; ++rt) z1a[rt] = (f32x4){0.f, 0.f, 0.f, 0.f};
#pragma unroll
    for (int half = 0; half < 2; ++half) {
      const int s0 = half * 4;
      u64 lo[16], hi[16];
#pragma unroll
      for (int i = 0; i < 16; ++i) {
        const int s = s0 + (i >> 2), rt = i & 3;
        const int idx = (v * 32 + s * 4 + oct) * 64 + rt * 16 + n;
        lo[i] = ALOAD(h0b + idx);
        hi[i] = ALOAD(h0b + HWORDS + idx);
      }
#pragma unroll
      for (int sj = 0; sj < 4; ++sj) {
        const int kp = v * 256 + (s0 + sj) * 32 + oct * 8;
        bf16x8 bw = *(const bf16x8*)&lw1[n * P1 + kp];
#pragma unroll
        for (int rt = 0; rt < 4; ++rt) {
          frag_u u; u.q[0] = lo[sj * 4 + rt]; u.q[1] = hi[sj * 4 + rt];
          z1a[rt] = MFMA16(u.f, bw, z1a[rt]);
        }
      }
    }
    bar_wait(flagsB, 256u);             // h1(254), parity 0
    const u64* h1b = h1s + (size_t)(0 * 2) * HWORDS;
#pragma unroll
    for (int half = 0; half < 2; ++half) {
      const int s0 = half * 4;
      u64 lo[16], hi[16];
#pragma unroll
      for (int i = 0; i < 16; ++i) {
        const int s = s0 + (i >> 2), rt = i & 3;
        const int idx = (v * 32 + s * 4 + oct) * 64 + rt * 16 + n;
        lo[i] = ALOAD(h1b + idx);
        hi[i] = ALOAD(h1b + HWORDS + idx);
      }
#pragma unroll
      for (int sj = 0; sj < 4; ++sj) {
        const int kp = v * 256 + (s0 + sj) * 32 + oct * 8;
        bf16x8 bw = *(const bf16x8*)&lw1[n * P1 + 1024 + kp];
#pragma unroll
        for (int rt = 0; rt < 4; ++rt) {
          frag_u u; u.q[0] = lo[sj * 4 + rt]; u.q[1] = hi[sj * 4 + rt];
          z1a[rt] = MFMA16(u.f, bw, z1a[rt]);
        }
      }
    }
    zreduce(z1a);
    hs[mg][hq] = gates(zv, b1r, S1, c1r, false);
    __syncthreads();
    publish(h1s + (size_t)(1 * 2) * HWORDS);   // h1(255), parity 1
    flag_release(flagsB, 257u);
  }

  // ============ final FC: out = h1(255) @ Wfc + bfc (blocks 0..31) ============
  if (wg < DOUT / 16) {
    bar_wait(flagsB, 257u);
    {  // stage Wfc cols [wg*16, wg*16+16) into lw0 region (fp32 -> bf16)
      const int q = tid >> 6, kw = tid & 63;
      for (int k = kw; k < HH; k += 64) {
        float4 u = *(const float4*)(Wfc + (size_t)k * DOUT + wg * 16 + q * 4);
        lw0[(q * 4 + 0) * P0 + k] = (unsigned short)f2b(u.x);
        lw0[(q * 4 + 1) * P0 + k] = (unsigned short)f2b(u.y);
        lw0[(q * 4 + 2) * P0 + k] = (unsigned short)f2b(u.z);
        lw0[(q * 4 + 3) * P0 + k] = (unsigned short)f2b(u.w);
      }
    }
    __syncthreads();
    const u64* hb = h1s + (size_t)(1 * 2) * HWORDS;   // h1(255), parity 1
    f32x4 acc0 = {0.f, 0.f, 0.f, 0.f}, acc1 = {0.f, 0.f, 0.f, 0.f};
#pragma unroll
    for (int it = 0; it < 16; ++it) {
      const int idxA = (it * 8 + oct) * 64 + v * 16 + n;
      const int idxB = (it * 8 + 4 + oct) * 64 + v * 16 + n;
      frag_u uA, uB;
      uA.q[0] = ALOAD(hb + idxA); uA.q[1] = ALOAD(hb + HWORDS + idxA);
      uB.q[0] = ALOAD(hb + idxB); uB.q[1] = ALOAD(hb + HWORDS + idxB);
      bf16x8 bwA = *(const bf16x8*)&lw0[n * P0 + it * 64 + oct * 8];
      bf16x8 bwB = *(const bf16x8*)&lw0[n * P0 + it * 64 + 32 + oct * 8];
      acc0 = MFMA16(uA.f, bwA, acc0);
      acc1 = MFMA16(uB.f, bwB, acc1);
    }
    float bb = bfc[wg * 16 + n];
#pragma unroll
    for (int r = 0; r < 4; ++r) {
      int row = v * 16 + oct * 4 + r;
      out[(size_t)row * DOUT + wg * 16 + n] = acc0[r] + acc1[r] + bb;
    }
  }
}

extern "C" void kernel_launch(void* const* d_in, const int* in_sizes, int n_in,
                              void* d_out, int out_size, void* d_ws, size_t ws_size,
                              hipStream_t stream) {
  const float* x   = (const float*)d_in[0];
  const float* W0  = (const float*)d_in[1];
  const float* b0  = (const float*)d_in[2];
  const float* W1  = (const float*)d_in[3];
  const float* b1  = (const float*)d_in[4];
  const float* Wfc = (const float*)d_in[5];
  const float* bfc = (const float*)d_in[6];

  // ---- workspace (~516 KB): flags + split-octet h buffers ----
  char* ws = (char*)d_ws;
  unsigned* flagsA = (unsigned*)ws;             // 256 u32
  unsigned* flagsB = (unsigned*)(ws + 1024);    // 256 u32
  u64* h0s = (u64*)(ws + 4096);                 // [parity][half][8192] u64 = 256 KB
  u64* h1s = h0s + 4 * HWORDS;                  // 256 KB

  hipMemsetAsync(ws, 0, 4096, stream);          // zero both flag arrays

  lstm_persist<<<dim3(256), dim3(256), 0, stream>>>(
      x, W0, b0, W1, b1, Wfc, bfc, h0s, h1s, flagsA, flagsB, (float*)d_out);
}

// Round 7
// 2208.146 us; speedup vs baseline: 2.4811x; 1.2408x over previous
//
#include <hip/hip_runtime.h>
#include <hip/hip_bf16.h>

typedef __attribute__((ext_vector_type(8))) short bf16x8;   // MFMA A/B frag (16B)
typedef __attribute__((ext_vector_type(4))) float f32x4;    // MFMA C/D frag
using bf16 = __hip_bfloat16;
typedef unsigned long long u64;

constexpr int BB = 64, TT = 256, DIN = 512, HH = 1024, DOUT = 512;
constexpr int P0 = 1544;       // LDS pitch for W0 rows (1536 + 8)
constexpr int P1 = 2056;       // LDS pitch for W1 rows (2048 + 8)
constexpr int HWORDS = 8192;   // one h half-array: 128 koct x 64 rows (u64)
constexpr int NW = 8;          // waves per block (2 per SIMD -> TLP)

#define MFMA16(a, b, c) __builtin_amdgcn_mfma_f32_16x16x32_bf16((a), (b), (c), 0, 0, 0)
#define ALOAD(p)  __hip_atomic_load((p),  __ATOMIC_RELAXED, __HIP_MEMORY_SCOPE_AGENT)
#define ASTORE(p, v) __hip_atomic_store((p), (v), __ATOMIC_RELAXED, __HIP_MEMORY_SCOPE_AGENT)

union frag_u { u64 q[2]; bf16x8 f; };

__device__ __forceinline__ short f2b(float f) {
  __hip_bfloat16 h = __float2bfloat16(f);           // RNE
  return *reinterpret_cast<short*>(&h);
}
__device__ __forceinline__ u64 pack4(float4 v) {
  return (u64)(unsigned short)f2b(v.x) | ((u64)(unsigned short)f2b(v.y) << 16) |
         ((u64)(unsigned short)f2b(v.z) << 32) | ((u64)(unsigned short)f2b(v.w) << 48);
}

// gate math: z -> (h bf16 bits), updates c register
__device__ __forceinline__ unsigned short gates(const float zv[4], const float br[4],
                                                float scale, float& cr, bool first) {
  float zf = (zv[0] + br[0]) * scale;
  float zi = (zv[1] + br[1]) * scale;
  float zo = (zv[2] + br[2]) * scale;
  float zg = (zv[3] + br[3]) * scale;
  float f = 1.0f / (1.0f + __expf(-zf));
  float i = 1.0f / (1.0f + __expf(-zi));
  float o = 1.0f / (1.0f + __expf(-zo));
  float g = tanhf(zg);
  float cn = f * (first ? 0.0f : cr) + i * g;
  cr = cn;
  __hip_bfloat16 hv = __float2bfloat16(o * tanhf(cn));
  return *reinterpret_cast<unsigned short*>(&hv);
}

// ---------------- persistent kernel: 256 blocks x 512 threads (8 waves), 1 block/CU --------
// Block wg owns h-cols [4wg,4wg+4) -> its 16 z-cols. 8 waves split K (128/wave for h GEMMs)
// giving 2 waves/SIMD: TLP hides sc1/L3 latency that ILP alone could not (round-5 lesson).
// Fence-free coherence: h via agent-scope relaxed atomics in split-octet layout; x converted
// once to bf16 [t][koct][row] (sc1 stores + epoch barrier), then read with normal cached loads.
__global__ void __launch_bounds__(512, 1)
lstm_persist(const float* __restrict__ x,  const float* __restrict__ W0,
             const float* __restrict__ b0, const float* __restrict__ W1,
             const float* __restrict__ b1, const float* __restrict__ Wfc,
             const float* __restrict__ bfc,
             u64* __restrict__ xbu, int use_xb,
             u64* __restrict__ h0s, u64* __restrict__ h1s,
             unsigned* __restrict__ flagsA, unsigned* __restrict__ flagsB,
             float* __restrict__ out) {
  __shared__ unsigned short lw0[16 * P0];            // 49.4 KB  W0^T cols, bf16
  __shared__ unsigned short lw1[16 * P1];            // 65.8 KB  W1^T cols, bf16
  __shared__ float zbuf[NW][4][16][17];              // 34.8 KB  cross-wave z partials
  __shared__ unsigned short hs[64][4];               // 0.5 KB   h-tile staging

  const int tid  = threadIdx.x;
  const int wg   = blockIdx.x;
  const int lane = tid & 63;
  const int wv   = tid >> 6;          // wave id 0..7 = K-eighth
  const int n    = lane & 15;
  const int oct  = lane >> 4;
  const int mg   = tid & 63;          // epilogue row (tid<256 only)
  const int hq   = tid >> 6;          // epilogue hcol offset (tid<256 only)
  const float S0 = 1.0f / sqrtf((float)(DIN + HH));
  const float S1 = 1.0f / sqrtf((float)(HH + HH));

  float c0r = 0.0f, c1r = 0.0f;
  float b0r[4] = {0, 0, 0, 0}, b1r[4] = {0, 0, 0, 0};
  if (tid < 256) {
    const int hcol = wg * 4 + hq;
#pragma unroll
    for (int g = 0; g < 4; ++g) { b0r[g] = b0[g * HH + hcol]; b1r[g] = b1[g * HH + hcol]; }
  }

  // ---- stage this block's 16 columns of W0/W1 into LDS (fp32 -> bf16, transposed) ----
  {
    const int g = tid >> 7, kw = tid & 127;
    const int col0 = g * HH + wg * 4;
    for (int k = kw; k < DIN + HH; k += 128) {
      float4 u = *(const float4*)(W0 + (size_t)k * 4096 + col0);
      lw0[(g * 4 + 0) * P0 + k] = (unsigned short)f2b(u.x);
      lw0[(g * 4 + 1) * P0 + k] = (unsigned short)f2b(u.y);
      lw0[(g * 4 + 2) * P0 + k] = (unsigned short)f2b(u.z);
      lw0[(g * 4 + 3) * P0 + k] = (unsigned short)f2b(u.w);
    }
    for (int k = kw; k < 2 * HH; k += 128) {
      float4 u = *(const float4*)(W1 + (size_t)k * 4096 + col0);
      lw1[(g * 4 + 0) * P1 + k] = (unsigned short)f2b(u.x);
      lw1[(g * 4 + 1) * P1 + k] = (unsigned short)f2b(u.y);
      lw1[(g * 4 + 2) * P1 + k] = (unsigned short)f2b(u.z);
      lw1[(g * 4 + 3) * P1 + k] = (unsigned short)f2b(u.w);
    }
  }

  // ---- epoch 0: convert x -> bf16 split layout xb[t][koct 64][row 64] (16B units) ----
  if (use_xb) {
    const int t = wg;                 // block wg converts timestep wg
    for (int u = tid; u < 64 * 64; u += 512) {
      const int row = u & 63, ko = u >> 6;
      const float* p = x + ((size_t)row * TT + t) * DIN + ko * 8;
      float4 A = *(const float4*)p, B = *(const float4*)(p + 4);
      u64* d = xbu + ((size_t)(t * 64 + ko) * 64 + row) * 2;
      ASTORE(d, pack4(A));
      ASTORE(d + 1, pack4(B));
    }
  }
  __syncthreads();                    // drains conv stores (vmcnt 0 before barrier) + LDS staging

  f32x4 z0a[4], z1a[4];
  float zv[4] = {0, 0, 0, 0};

  auto flag_release = [&](unsigned* f, unsigned val) {
    if (tid < 64) __builtin_amdgcn_s_waitcnt(0);     // wave0: drain its sc1 stores
    if (tid == 0) ASTORE(f + wg, val);
  };
  auto bar_wait = [&](unsigned* f, unsigned target) {
    if (tid < 64) {                                  // wave 0 polls 4 flags/thread
      const u64* p = (const u64*)(f + tid * 4);
      for (;;) {
        u64 a = ALOAD(p), b = ALOAD(p + 1);
        if ((unsigned)a >= target && (unsigned)(a >> 32) >= target &&
            (unsigned)b >= target && (unsigned)(b >> 32) >= target) break;
        __builtin_amdgcn_s_sleep(1);
      }
    }
    __syncthreads();
    __builtin_amdgcn_fence(__ATOMIC_ACQUIRE, "workgroup");   // ordering only
  };

  flag_release(flagsA, 1u);           // x conversion published
  bar_wait(flagsA, 1u);

  // ---- x-part of layer0(t): 8 cached 16B loads + 8 MFMA per wave ----
  auto xpart = [&](int t) {
    if (use_xb) {
      const bf16* xb = (const bf16*)xbu;
#pragma unroll
      for (int s = 0; s < 2; ++s) {
        const int ko = wv * 8 + s * 4 + oct;
        bf16x8 bw = *(const bf16x8*)&lw0[n * P0 + ko * 8];
#pragma unroll
        for (int rt = 0; rt < 4; ++rt) {
          bf16x8 a = *(const bf16x8*)(xb + ((size_t)(t * 64 + ko) * 64 + rt * 16 + n) * 8);
          z0a[rt] = MFMA16(a, bw, z0a[rt]);
        }
      }
    } else {                          // fallback: fp32 x + on-the-fly cvt
#pragma unroll
      for (int s = 0; s < 2; ++s) {
        const int kp = wv * 64 + s * 32 + oct * 8;
        bf16x8 bw = *(const bf16x8*)&lw0[n * P0 + kp];
#pragma unroll
        for (int rt = 0; rt < 4; ++rt) {
          const float* p = x + ((size_t)(rt * 16 + n) * TT + t) * DIN + kp;
          float4 A = *(const float4*)p, B = *(const float4*)(p + 4);
          bf16x8 a;
          a[0] = f2b(A.x); a[1] = f2b(A.y); a[2] = f2b(A.z); a[3] = f2b(A.w);
          a[4] = f2b(B.x); a[5] = f2b(B.y); a[6] = f2b(B.z); a[7] = f2b(B.w);
          z0a[rt] = MFMA16(a, bw, z0a[rt]);
        }
      }
    }
  };

  // h0 dual-consume GEMM: z0 += h0*W0[512+k], z1 += h0*W1[k]  (16 frags/wave)
  auto h0gemm = [&](const u64* h0b) {
    u64 lo[16], hi[16];
#pragma unroll
    for (int i = 0; i < 16; ++i) {
      const int s = i >> 2, rt = i & 3;
      const int idx = (wv * 16 + s * 4 + oct) * 64 + rt * 16 + n;
      lo[i] = ALOAD(h0b + idx);
      hi[i] = ALOAD(h0b + HWORDS + idx);
    }
#pragma unroll
    for (int s = 0; s < 4; ++s) {
      const int kp = wv * 128 + s * 32 + oct * 8;
      bf16x8 bw0 = *(const bf16x8*)&lw0[n * P0 + 512 + kp];
      bf16x8 bw1 = *(const bf16x8*)&lw1[n * P1 + kp];
#pragma unroll
      for (int rt = 0; rt < 4; ++rt) {
        frag_u u; u.q[0] = lo[s * 4 + rt]; u.q[1] = hi[s * 4 + rt];
        z0a[rt] = MFMA16(u.f, bw0, z0a[rt]);
        z1a[rt] = MFMA16(u.f, bw1, z1a[rt]);
      }
    }
  };
  // z1 += h * W1[koff + k]
  auto h1gemm = [&](const u64* hb, int koff) {
    u64 lo[16], hi[16];
#pragma unroll
    for (int i = 0; i < 16; ++i) {
      const int s = i >> 2, rt = i & 3;
      const int idx = (wv * 16 + s * 4 + oct) * 64 + rt * 16 + n;
      lo[i] = ALOAD(hb + idx);
      hi[i] = ALOAD(hb + HWORDS + idx);
    }
#pragma unroll
    for (int s = 0; s < 4; ++s) {
      const int kp = wv * 128 + s * 32 + oct * 8;
      bf16x8 bw = *(const bf16x8*)&lw1[n * P1 + koff + kp];
#pragma unroll
      for (int rt = 0; rt < 4; ++rt) {
        frag_u u; u.q[0] = lo[s * 4 + rt]; u.q[1] = hi[s * 4 + rt];
        z1a[rt] = MFMA16(u.f, bw, z1a[rt]);
      }
    }
  };

  auto publish = [&](u64* dst) {
    if (tid < 64) {
      u64 val = *(const u64*)&hs[tid][0];
      ASTORE(dst + (size_t)(wg & 1) * HWORDS + (wg >> 1) * 64 + tid, val);
    }
  };
  auto zreduce = [&](f32x4 za[4]) {
#pragma unroll
    for (int rt = 0; rt < 4; ++rt)
#pragma unroll
      for (int r = 0; r < 4; ++r) zbuf[wv][rt][oct * 4 + r][n] = za[rt][r];
    __syncthreads();
    if (tid < 256) {
#pragma unroll
      for (int g = 0; g < 4; ++g) {
        float s = 0.f;
#pragma unroll
        for (int w = 0; w < NW; ++w) s += zbuf[w][mg >> 4][mg & 15][g * 4 + hq];
        zv[g] = s;
      }
    }
  };

  // =================== window 0: layer0(0), x-part only ===================
#pragma unroll
  for (int rt = 0; rt < 4; ++rt) z0a[rt] = (f32x4){0.f, 0.f, 0.f, 0.f};
  xpart(0);
  zreduce(z0a);
  if (tid < 256) hs[mg][hq] = gates(zv, b0r, S0, c0r, true);
  __syncthreads();
  publish(h0s);                       // h0(0), parity 0
  flag_release(flagsA, 2u);
  flag_release(flagsB, 1u);           // vacuous
#pragma unroll
  for (int rt = 0; rt < 4; ++rt) z0a[rt] = (f32x4){0.f, 0.f, 0.f, 0.f};
  xpart(1);

  // =================== windows 1..255 ===================
  for (int t = 1; t < TT; ++t) {
    bar_wait(flagsA, (unsigned)t + 1u);             // h0(t-1) visible
    const u64* h0b = h0s + (size_t)(((t - 1) & 1) * 2) * HWORDS;
#pragma unroll
    for (int rt = 0; rt < 4; ++rt) z1a[rt] = (f32x4){0.f, 0.f, 0.f, 0.f};
    h0gemm(h0b);

    zreduce(z0a);                                   // z0 complete
    if (tid < 256) hs[mg][hq] = gates(zv, b0r, S0, c0r, false);
    __syncthreads();
    publish(h0s + (size_t)((t & 1) * 2) * HWORDS);  // h0(t)
    flag_release(flagsA, (unsigned)t + 2u);         // release h0 chain EARLY

    if (t < TT - 1) {                               // overlap x(t+1)
#pragma unroll
      for (int rt = 0; rt < 4; ++rt) z0a[rt] = (f32x4){0.f, 0.f, 0.f, 0.f};
      xpart(t + 1);
    }

    if (t >= 2) {
      bar_wait(flagsB, (unsigned)t);                // h1(t-2) visible
      h1gemm(h1s + (size_t)((t & 1) * 2) * HWORDS, 1024);
    }
    zreduce(z1a);
    if (tid < 256) hs[mg][hq] = gates(zv, b1r, S1, c1r, t == 1);
    __syncthreads();
    publish(h1s + (size_t)(((t - 1) & 1) * 2) * HWORDS);  // h1(t-1)
    flag_release(flagsB, (unsigned)t + 1u);
  }

  // =================== final window: layer1(255) ===================
  {
    bar_wait(flagsA, 257u);                         // h0(255), parity 1
#pragma unroll
    for (int rt = 0; rt < 4; ++rt) z1a[rt] = (f32x4){0.f, 0.f, 0.f, 0.f};
    h1gemm(h0s + 2 * HWORDS, 0);                    // z1 += h0(255) * W1lo
    bar_wait(flagsB, 256u);                         // h1(254), parity 0
    h1gemm(h1s, 1024);                              // z1 += h1(254) * W1hi
    zreduce(z1a);
    if (tid < 256) hs[mg][hq] = gates(zv, b1r, S1, c1r, false);
    __syncthreads();
    publish(h1s + 2 * HWORDS);                      // h1(255), parity 1
    flag_release(flagsB, 257u);
  }

  // ============ final FC: out = h1(255) @ Wfc + bfc (blocks 0..31) ============
  if (wg < DOUT / 16) {
    bar_wait(flagsB, 257u);
    {  // stage Wfc cols [wg*16, wg*16+16) into lw0 region (fp32 -> bf16)
      const int q = tid >> 7, kw = tid & 127;
      for (int k = kw; k < HH; k += 128) {
        float4 u = *(const float4*)(Wfc + (size_t)k * DOUT + wg * 16 + q * 4);
        lw0[(q * 4 + 0) * P0 + k] = (unsigned short)f2b(u.x);
        lw0[(q * 4 + 1) * P0 + k] = (unsigned short)f2b(u.y);
        lw0[(q * 4 + 2) * P0 + k] = (unsigned short)f2b(u.z);
        lw0[(q * 4 + 3) * P0 + k] = (unsigned short)f2b(u.w);
      }
    }
    __syncthreads();
    if (tid < 256) {
      const int v4 = tid >> 6;                      // 0..3 (waves 0-3 do the FC)
      const u64* hb = h1s + 2 * HWORDS;             // h1(255)
      f32x4 acc0 = {0.f, 0.f, 0.f, 0.f}, acc1 = {0.f, 0.f, 0.f, 0.f};
#pragma unroll
      for (int it = 0; it < 16; ++it) {
        const int idxA = (it * 8 + oct) * 64 + v4 * 16 + n;
        const int idxB = (it * 8 + 4 + oct) * 64 + v4 * 16 + n;
        frag_u uA, uB;
        uA.q[0] = ALOAD(hb + idxA); uA.q[1] = ALOAD(hb + HWORDS + idxA);
        uB.q[0] = ALOAD(hb + idxB); uB.q[1] = ALOAD(hb + HWORDS + idxB);
        bf16x8 bwA = *(const bf16x8*)&lw0[n * P0 + it * 64 + oct * 8];
        bf16x8 bwB = *(const bf16x8*)&lw0[n * P0 + it * 64 + 32 + oct * 8];
        acc0 = MFMA16(uA.f, bwA, acc0);
        acc1 = MFMA16(uB.f, bwB, acc1);
      }
      float bb = bfc[wg * 16 + n];
#pragma unroll
      for (int r = 0; r < 4; ++r) {
        int row = v4 * 16 + oct * 4 + r;
        out[(size_t)row * DOUT + wg * 16 + n] = acc0[r] + acc1[r] + bb;
      }
    }
  }
}

extern "C" void kernel_launch(void* const* d_in, const int* in_sizes, int n_in,
                              void* d_out, int out_size, void* d_ws, size_t ws_size,
                              hipStream_t stream) {
  const float* x   = (const float*)d_in[0];
  const float* W0  = (const float*)d_in[1];
  const float* b0  = (const float*)d_in[2];
  const float* W1  = (const float*)d_in[3];
  const float* b1  = (const float*)d_in[4];
  const float* Wfc = (const float*)d_in[5];
  const float* bfc = (const float*)d_in[6];

  // ---- workspace: flags (4KB) + h buffers (512KB) + xb (16.78MB) ----
  char* ws = (char*)d_ws;
  unsigned* flagsA = (unsigned*)ws;                   // 256 u32
  unsigned* flagsB = (unsigned*)(ws + 1024);          // 256 u32
  u64* h0s = (u64*)(ws + 4096);                       // 4*HWORDS u64 = 256 KB
  u64* h1s = h0s + 4 * HWORDS;                        // 256 KB
  u64* xbu = h1s + 4 * HWORDS;                        // 256*64*64 units * 16B = 16.78 MB
  size_t needed = 4096 + 2 * 4 * (size_t)HWORDS * 8 + (size_t)TT * 64 * 64 * 16;
  int use_xb = (ws_size >= needed) ? 1 : 0;

  hipMemsetAsync(ws, 0, 4096, stream);                // zero both flag arrays

  lstm_persist<<<dim3(256), dim3(512), 0, stream>>>(
      x, W0, b0, W1, b1, Wfc, bfc, xbu, use_xb, h0s, h1s, flagsA, flagsB, (float*)d_out);
}